// Round 4
// baseline (127.401 us; speedup 1.0000x reference)
//
#include <hip/hip_runtime.h>

#define NB 8
#define NS 2048
#define ND 64
#define LOG2E 1.44269504f
// int16 Q8.8 logit slab: step 2^-8 in log2-units (~0.27% rel on p), range +-125
#define QSC 256.0f
#define IQS (1.0f / 256.0f)

typedef _Float16 half8 __attribute__((ext_vector_type(8)));
typedef _Float16 half4 __attribute__((ext_vector_type(4)));
typedef __attribute__((ext_vector_type(4))) float floatx4;

__device__ __forceinline__ half8 cvt8(const float* p) {
    float4 a = *(const float4*)p;
    float4 b = *(const float4*)(p + 4);
    half8 h = {(_Float16)a.x, (_Float16)a.y, (_Float16)a.z, (_Float16)a.w,
               (_Float16)b.x, (_Float16)b.y, (_Float16)b.z, (_Float16)b.w};
    return h;
}

// ---------------- W prep: fp32 [d][c] -> fp16 Wt[m][c][d] (B-frag friendly) --
__global__ __launch_bounds__(256) void wprep(
    const float* __restrict__ Wq, const float* __restrict__ Wk,
    const float* __restrict__ Wv, _Float16* __restrict__ Wt)
{
    const int m = blockIdx.x;
    const float* W = (m == 0) ? Wq : (m == 1) ? Wk : Wv;
    for (int i = threadIdx.x; i < 64 * 64; i += 256) {
        const int c = i >> 6, d = i & 63;
        Wt[((size_t)m * 64 + c) * 64 + d] = (_Float16)W[d * 64 + c];
    }
}

// ---------------- QKV projection: 64 rows/block, vector fp16 W loads ---------
__global__ __launch_bounds__(256) void qkv_proj(
    const float* __restrict__ x, const _Float16* __restrict__ Wt,
    const float* __restrict__ bq, const float* __restrict__ bk,
    const float* __restrict__ bv,
    _Float16* __restrict__ Qg, _Float16* __restrict__ Kg,
    _Float16* __restrict__ Vt)
{
    __shared__ _Float16 vt[4][64 * 20];   // per-wave V^T staging [col][row]

    const int tid  = threadIdx.x;
    const int wv   = tid >> 6;
    const int l    = tid & 63;
    const int quad = l >> 4;
    const int tx   = l & 15;

    const int b  = blockIdx.x & 7;                  // XCD-pinned batch
    const int n0 = (blockIdx.x >> 3) * 64 + wv * 16;

    const float* xr = x + ((size_t)b * NS + n0 + tx) * ND + quad * 8;
    half8 a0 = cvt8(xr);
    half8 a1 = cvt8(xr + 32);

    const floatx4 zf = {0.f, 0.f, 0.f, 0.f};

#pragma unroll
    for (int ctile = 0; ctile < 12; ++ctile) {
        const int m    = ctile >> 2;
        const int lcol = (ctile & 3) * 16 + tx;

        const _Float16* Wb = Wt + ((size_t)m * 64 + lcol) * 64;
        half8 b0 = *(const half8*)(Wb + quad * 8);
        half8 b1 = *(const half8*)(Wb + 32 + quad * 8);

        floatx4 acc = __builtin_amdgcn_mfma_f32_16x16x32_f16(a0, b0, zf, 0, 0, 0);
        acc = __builtin_amdgcn_mfma_f32_16x16x32_f16(a1, b1, acc, 0, 0, 0);

        const float* Bp = (m == 0) ? bq : (m == 1) ? bk : bv;
        const float bias = Bp[lcol];

        if (m == 0) {
#pragma unroll
            for (int r = 0; r < 4; ++r)
                Qg[((size_t)b * NS + n0 + quad * 4 + r) * ND + lcol] =
                    (_Float16)((acc[r] + bias) * LOG2E);
        } else if (m == 1) {
#pragma unroll
            for (int r = 0; r < 4; ++r)
                Kg[((size_t)b * NS + n0 + quad * 4 + r) * ND + lcol] =
                    (_Float16)(acc[r] + bias);
        } else {
#pragma unroll
            for (int r = 0; r < 4; ++r)
                vt[wv][lcol * 20 + quad * 4 + r] = (_Float16)(acc[r] + bias);
        }
    }
    __syncthreads();
    {
        const int d = l;
        const _Float16* src = &vt[wv][d * 20];
        uint2 p0 = *(const uint2*)(src);
        uint2 p1 = *(const uint2*)(src + 4);
        uint2 p2 = *(const uint2*)(src + 8);
        uint2 p3 = *(const uint2*)(src + 12);
        uint4 q0 = {p0.x, p0.y, p1.x, p1.y};
        uint4 q1 = {p2.x, p2.y, p3.x, p3.y};
        _Float16* dst = Vt + ((size_t)b * ND + d) * NS + n0;
        *(uint4*)(dst)     = q0;
        *(uint4*)(dst + 8) = q1;
    }
}

// ---------------- fused masked attention: barrier-free, wave-private slabs ---
// Block = 32 q-rows x 512 thr (8 waves), grid 512 (b = blk&7 XCD-pinned).
// Wave (e = wv>>2, kq = wv&3) owns keys {(2*tl+e)*64 + kq*16 + 0..15, tl=0..15}
// -> 256 keys/wave, disjoint. K/V per batch (512KB) is XCD-L2-resident: no LDS
// staging, no main-loop barriers. Fragments read direct from L2 with 2-deep
// register prefetch.
// Pass 1: swapped QK mfma(kf, qf[rh]) -> lane(quad,tx) reg r =
//   score[key=quad*4+r][qrow=rh*16+tx]; quantize to int16 Q8.8, store to the
//   wave-private LDS slab psl[wv][32][264] (row stride 264: 2-way banks);
//   L accumulated from QUANTIZED scores (consistent softmax, round-1 verified).
//   Reduce quads via shfl_xor(16/32), merge 8 wave-partials via lsh[row][8].
// Pass 2: read slab back (b64), e=exp2(q/256), w = e>L/N ? e/L : 0; the lane's
//   4 w's ARE the A-frag of v_mfma_f32_16x16x16_f16 -> PV direct from regs.
//   o[rh][dg] = rows rh*16, all 64 dims, wave's 256 keys. 3-round LDS tree
//   merge over 8 waves at the end (osm overlays the slab). Barriers: 69 -> 6.
__global__ __launch_bounds__(512, 2) void attn(
    const _Float16* __restrict__ Qg,
    const _Float16* __restrict__ Kg,
    const _Float16* __restrict__ Vt,
    float* __restrict__ out)
{
    __shared__ short psl[8][32 * 264];   // 135.2KB wave-private Q8.8 logit slabs
    __shared__ float lsh[32 * 8];        // [row][wave] L partials

    const int tid  = threadIdx.x;
    const int wv   = tid >> 6;
    const int l    = tid & 63;
    const int quad = l >> 4;
    const int tx   = l & 15;
    const int e    = wv >> 2;       // tile parity
    const int kq   = wv & 3;        // key-quarter within tile

    const int b  = blockIdx.x & 7;
    const int q0 = (blockIdx.x >> 3) * 32;

    const _Float16* Qb = Qg + ((size_t)b * NS + q0) * ND;
    const _Float16* Kb = Kg + (size_t)b * NS * ND;
    const _Float16* Vb = Vt + (size_t)b * ND * NS;
    short* ps = psl[wv];

    // Q B-frags: rows rh*16 + tx, k-chunks 0/1 (shared by all waves, L2-hot)
    half8 qf[2][2];
#pragma unroll
    for (int rh = 0; rh < 2; ++rh)
#pragma unroll
        for (int kc = 0; kc < 2; ++kc)
            qf[rh][kc] = *(const half8*)(Qb + (size_t)(rh * 16 + tx) * ND + kc * 32 + quad * 8);

    const floatx4 zf = {0.f, 0.f, 0.f, 0.f};

    // wave's K rows: key = (2*tl+e)*64 + kq*16 + tx  ->  base + tl*128*ND
    const _Float16* Kw = Kb + ((size_t)(e * 64 + kq * 16 + tx)) * ND;

    // ================= pass 1: QK once, L + logit slab =================
    float lacc0 = 0.f, lacc1 = 0.f;
    {
        half8 kf0[2], kf1[2];
        kf0[0] = *(const half8*)(Kw + quad * 8);
        kf1[0] = *(const half8*)(Kw + 32 + quad * 8);
        kf0[1] = *(const half8*)(Kw + (size_t)128 * ND + quad * 8);
        kf1[1] = *(const half8*)(Kw + (size_t)128 * ND + 32 + quad * 8);
#pragma unroll
        for (int tl = 0; tl < 16; ++tl) {
            const int sl = tl & 1;
            half8 a0 = kf0[sl], a1 = kf1[sl];
            if (tl < 14) {
                kf0[sl] = *(const half8*)(Kw + (size_t)(tl + 2) * 128 * ND + quad * 8);
                kf1[sl] = *(const half8*)(Kw + (size_t)(tl + 2) * 128 * ND + 32 + quad * 8);
            }
#pragma unroll
            for (int rh = 0; rh < 2; ++rh) {
                floatx4 c = __builtin_amdgcn_mfma_f32_16x16x32_f16(a0, qf[rh][0], zf, 0, 0, 0);
                c = __builtin_amdgcn_mfma_f32_16x16x32_f16(a1, qf[rh][1], c, 0, 0, 0);
                int ic[4];
                float ladd = 0.f;
#pragma unroll
                for (int r = 0; r < 4; ++r) {
                    float cs = fminf(fmaxf(c[r] * QSC, -32000.f), 32000.f);
                    int v = (int)rintf(cs);
                    ic[r] = v;
                    ladd += __builtin_amdgcn_exp2f((float)v * IQS);   // quantized-consistent L
                }
                if (rh == 0) lacc0 += ladd; else lacc1 += ladd;
                uint2 pk;
                pk.x = (unsigned)(ic[0] & 0xffff) | ((unsigned)ic[1] << 16);
                pk.y = (unsigned)(ic[2] & 0xffff) | ((unsigned)ic[3] << 16);
                *(uint2*)&ps[(rh * 16 + tx) * 264 + tl * 16 + quad * 4] = pk;
            }
        }
    }
    // quad-reduce: lanes l, l^16, l^32 share qrow
#pragma unroll
    for (int off = 16; off < 64; off <<= 1) {
        lacc0 += __shfl_xor(lacc0, off);
        lacc1 += __shfl_xor(lacc1, off);
    }
    if (quad == 0) {
        lsh[tx * 8 + wv]        = lacc0;
        lsh[(16 + tx) * 8 + wv] = lacc1;
    }
    __syncthreads();                                // lsh ready (only barrier pre-merge)

    float thr0, inv0, thr1, inv1;
    {
        float4 s0a = *(const float4*)&lsh[tx * 8];
        float4 s0b = *(const float4*)&lsh[tx * 8 + 4];
        float4 s1a = *(const float4*)&lsh[(16 + tx) * 8];
        float4 s1b = *(const float4*)&lsh[(16 + tx) * 8 + 4];
        float L0 = s0a.x + s0a.y + s0a.z + s0a.w + s0b.x + s0b.y + s0b.z + s0b.w;
        float L1 = s1a.x + s1a.y + s1a.z + s1a.w + s1b.x + s1b.y + s1b.z + s1b.w;
        inv0 = 1.f / L0;  thr0 = L0 * (1.f / (float)NS);
        inv1 = 1.f / L1;  thr1 = L1 * (1.f / (float)NS);
    }

    // ================= pass 2: mask + PV (no barriers) =================
    // V B-frag: B[k=quad*4+j][n=dim dg*16+tx] = Vt[dim][key]; key base folded:
    const _Float16* Vw = Vb + (size_t)tx * NS + e * 64 + kq * 16 + quad * 4;

    floatx4 o[2][4] = {{zf, zf, zf, zf}, {zf, zf, zf, zf}};
    {
        uint2 P0[2], P1[2];
        half4 Vf[2][4];
        P0[0] = *(const uint2*)&ps[tx * 264 + quad * 4];
        P1[0] = *(const uint2*)&ps[(16 + tx) * 264 + quad * 4];
        P0[1] = *(const uint2*)&ps[tx * 264 + 16 + quad * 4];
        P1[1] = *(const uint2*)&ps[(16 + tx) * 264 + 16 + quad * 4];
#pragma unroll
        for (int dg = 0; dg < 4; ++dg) {
            Vf[0][dg] = *(const half4*)(Vw + (size_t)(dg * 16) * NS);
            Vf[1][dg] = *(const half4*)(Vw + (size_t)(dg * 16) * NS + 128);
        }
#pragma unroll
        for (int tl = 0; tl < 16; ++tl) {
            const int sl = tl & 1;
            uint2 u0 = P0[sl], u1 = P1[sl];
            half4 v0 = Vf[sl][0], v1 = Vf[sl][1], v2 = Vf[sl][2], v3 = Vf[sl][3];
            if (tl < 14) {
                P0[sl] = *(const uint2*)&ps[tx * 264 + (tl + 2) * 16 + quad * 4];
                P1[sl] = *(const uint2*)&ps[(16 + tx) * 264 + (tl + 2) * 16 + quad * 4];
#pragma unroll
                for (int dg = 0; dg < 4; ++dg)
                    Vf[sl][dg] = *(const half4*)(Vw + (size_t)(dg * 16) * NS + (tl + 2) * 128);
            }
            half4 af0, af1;
            {
                int s0 = (int)(short)(u0.x), s1 = (int)(short)(u0.x >> 16);
                int s2 = (int)(short)(u0.y), s3 = (int)(short)(u0.y >> 16);
                float e0 = __builtin_amdgcn_exp2f((float)s0 * IQS);
                float e1 = __builtin_amdgcn_exp2f((float)s1 * IQS);
                float e2 = __builtin_amdgcn_exp2f((float)s2 * IQS);
                float e3 = __builtin_amdgcn_exp2f((float)s3 * IQS);
                af0[0] = (_Float16)((e0 > thr0) ? e0 * inv0 : 0.f);
                af0[1] = (_Float16)((e1 > thr0) ? e1 * inv0 : 0.f);
                af0[2] = (_Float16)((e2 > thr0) ? e2 * inv0 : 0.f);
                af0[3] = (_Float16)((e3 > thr0) ? e3 * inv0 : 0.f);
            }
            {
                int s0 = (int)(short)(u1.x), s1 = (int)(short)(u1.x >> 16);
                int s2 = (int)(short)(u1.y), s3 = (int)(short)(u1.y >> 16);
                float e0 = __builtin_amdgcn_exp2f((float)s0 * IQS);
                float e1 = __builtin_amdgcn_exp2f((float)s1 * IQS);
                float e2 = __builtin_amdgcn_exp2f((float)s2 * IQS);
                float e3 = __builtin_amdgcn_exp2f((float)s3 * IQS);
                af1[0] = (_Float16)((e0 > thr1) ? e0 * inv1 : 0.f);
                af1[1] = (_Float16)((e1 > thr1) ? e1 * inv1 : 0.f);
                af1[2] = (_Float16)((e2 > thr1) ? e2 * inv1 : 0.f);
                af1[3] = (_Float16)((e3 > thr1) ? e3 * inv1 : 0.f);
            }
            o[0][0] = __builtin_amdgcn_mfma_f32_16x16x16f16(af0, v0, o[0][0], 0, 0, 0);
            o[0][1] = __builtin_amdgcn_mfma_f32_16x16x16f16(af0, v1, o[0][1], 0, 0, 0);
            o[0][2] = __builtin_amdgcn_mfma_f32_16x16x16f16(af0, v2, o[0][2], 0, 0, 0);
            o[0][3] = __builtin_amdgcn_mfma_f32_16x16x16f16(af0, v3, o[0][3], 0, 0, 0);
            o[1][0] = __builtin_amdgcn_mfma_f32_16x16x16f16(af1, v0, o[1][0], 0, 0, 0);
            o[1][1] = __builtin_amdgcn_mfma_f32_16x16x16f16(af1, v1, o[1][1], 0, 0, 0);
            o[1][2] = __builtin_amdgcn_mfma_f32_16x16x16f16(af1, v2, o[1][2], 0, 0, 0);
            o[1][3] = __builtin_amdgcn_mfma_f32_16x16x16f16(af1, v3, o[1][3], 0, 0, 0);
        }
    }

    // ================= 3-round tree merge over 8 waves, store =================
    __syncthreads();                                // all slab reads done; osm overlay safe
    float* osm = (float*)&psl[0][0];                // 4 slabs of [32][68] f32
    if (wv >= 4) {
        float* s = osm + (size_t)(wv - 4) * 32 * 68;
#pragma unroll
        for (int rh = 0; rh < 2; ++rh)
#pragma unroll
            for (int dg = 0; dg < 4; ++dg)
#pragma unroll
                for (int r = 0; r < 4; ++r)
                    s[(rh * 16 + quad * 4 + r) * 68 + dg * 16 + tx] = o[rh][dg][r];
    }
    __syncthreads();
    if (wv < 4) {
        const float* s = osm + (size_t)wv * 32 * 68;
#pragma unroll
        for (int rh = 0; rh < 2; ++rh)
#pragma unroll
            for (int dg = 0; dg < 4; ++dg)
#pragma unroll
                for (int r = 0; r < 4; ++r)
                    o[rh][dg][r] += s[(rh * 16 + quad * 4 + r) * 68 + dg * 16 + tx];
    }
    __syncthreads();
    if (wv == 2 || wv == 3) {
        float* s = osm + (size_t)(wv - 2) * 32 * 68;
#pragma unroll
        for (int rh = 0; rh < 2; ++rh)
#pragma unroll
            for (int dg = 0; dg < 4; ++dg)
#pragma unroll
                for (int r = 0; r < 4; ++r)
                    s[(rh * 16 + quad * 4 + r) * 68 + dg * 16 + tx] = o[rh][dg][r];
    }
    __syncthreads();
    if (wv < 2) {
        const float* s = osm + (size_t)wv * 32 * 68;
#pragma unroll
        for (int rh = 0; rh < 2; ++rh)
#pragma unroll
            for (int dg = 0; dg < 4; ++dg)
#pragma unroll
                for (int r = 0; r < 4; ++r)
                    o[rh][dg][r] += s[(rh * 16 + quad * 4 + r) * 68 + dg * 16 + tx];
    }
    __syncthreads();
    if (wv == 1) {
        float* s = osm;
#pragma unroll
        for (int rh = 0; rh < 2; ++rh)
#pragma unroll
            for (int dg = 0; dg < 4; ++dg)
#pragma unroll
                for (int r = 0; r < 4; ++r)
                    s[(rh * 16 + quad * 4 + r) * 68 + dg * 16 + tx] = o[rh][dg][r];
    }
    __syncthreads();
    if (wv == 0) {
#pragma unroll
        for (int rh = 0; rh < 2; ++rh)
#pragma unroll
            for (int dg = 0; dg < 4; ++dg)
#pragma unroll
                for (int r = 0; r < 4; ++r)
                    out[((size_t)b * NS + q0 + rh * 16 + quad * 4 + r) * ND + dg * 16 + tx] =
                        o[rh][dg][r] + osm[(rh * 16 + quad * 4 + r) * 68 + dg * 16 + tx];
    }
}

extern "C" void kernel_launch(void* const* d_in, const int* in_sizes, int n_in,
                              void* d_out, int out_size, void* d_ws, size_t ws_size,
                              hipStream_t stream) {
    const float* x  = (const float*)d_in[0];
    const float* Wq = (const float*)d_in[1];
    const float* bq = (const float*)d_in[2];
    const float* Wk = (const float*)d_in[3];
    const float* bk = (const float*)d_in[4];
    const float* Wv = (const float*)d_in[5];
    const float* bv = (const float*)d_in[6];

    // ws: Qg(2MB) Kg(2MB) Vt(2MB) Wt(24KB)
    _Float16* Qg = (_Float16*)d_ws;
    _Float16* Kg = Qg + (size_t)NB * NS * ND;
    _Float16* Vt = Kg + (size_t)NB * NS * ND;
    _Float16* Wt = Vt + (size_t)NB * NS * ND;

    wprep<<<3, 256, 0, stream>>>(Wq, Wk, Wv, Wt);
    qkv_proj<<<NB * (NS / 64), 256, 0, stream>>>(x, Wt, bq, bk, bv, Qg, Kg, Vt);
    attn<<<NB * (NS / 32), 512, 0, stream>>>(Qg, Kg, Vt, (float*)d_out);
}

// Round 5
// 113.458 us; speedup vs baseline: 1.1229x; 1.1229x over previous
//
#include <hip/hip_runtime.h>

#define NB 8
#define NS 2048
#define ND 64
#define LOG2E 1.44269504f

typedef _Float16 half8 __attribute__((ext_vector_type(8)));
typedef _Float16 half4 __attribute__((ext_vector_type(4)));
typedef __attribute__((ext_vector_type(4))) float floatx4;

__device__ __forceinline__ half8 cvt8(const float* p) {
    float4 a = *(const float4*)p;
    float4 b = *(const float4*)(p + 4);
    half8 h = {(_Float16)a.x, (_Float16)a.y, (_Float16)a.z, (_Float16)a.w,
               (_Float16)b.x, (_Float16)b.y, (_Float16)b.z, (_Float16)b.w};
    return h;
}

// ---------------- W prep: fp32 [d][c] -> fp16 Wt[m][c][d] (B-frag friendly) --
__global__ __launch_bounds__(256) void wprep(
    const float* __restrict__ Wq, const float* __restrict__ Wk,
    const float* __restrict__ Wv, _Float16* __restrict__ Wt)
{
    const int m = blockIdx.x;
    const float* W = (m == 0) ? Wq : (m == 1) ? Wk : Wv;
    for (int i = threadIdx.x; i < 64 * 64; i += 256) {
        const int c = i >> 6, d = i & 63;
        Wt[((size_t)m * 64 + c) * 64 + d] = (_Float16)W[d * 64 + c];
    }
}

// ---------------- QKV projection: 64 rows/block, vector fp16 W loads ---------
__global__ __launch_bounds__(256) void qkv_proj(
    const float* __restrict__ x, const _Float16* __restrict__ Wt,
    const float* __restrict__ bq, const float* __restrict__ bk,
    const float* __restrict__ bv,
    _Float16* __restrict__ Qg, _Float16* __restrict__ Kg,
    _Float16* __restrict__ Vt)
{
    __shared__ _Float16 vt[4][64 * 20];   // per-wave V^T staging [col][row]

    const int tid  = threadIdx.x;
    const int wv   = tid >> 6;
    const int l    = tid & 63;
    const int quad = l >> 4;
    const int tx   = l & 15;

    const int b  = blockIdx.x & 7;                  // XCD-pinned batch
    const int n0 = (blockIdx.x >> 3) * 64 + wv * 16;

    const float* xr = x + ((size_t)b * NS + n0 + tx) * ND + quad * 8;
    half8 a0 = cvt8(xr);
    half8 a1 = cvt8(xr + 32);

    const floatx4 zf = {0.f, 0.f, 0.f, 0.f};

#pragma unroll
    for (int ctile = 0; ctile < 12; ++ctile) {
        const int m    = ctile >> 2;
        const int lcol = (ctile & 3) * 16 + tx;

        const _Float16* Wb = Wt + ((size_t)m * 64 + lcol) * 64;
        half8 b0 = *(const half8*)(Wb + quad * 8);
        half8 b1 = *(const half8*)(Wb + 32 + quad * 8);

        floatx4 acc = __builtin_amdgcn_mfma_f32_16x16x32_f16(a0, b0, zf, 0, 0, 0);
        acc = __builtin_amdgcn_mfma_f32_16x16x32_f16(a1, b1, acc, 0, 0, 0);

        const float* Bp = (m == 0) ? bq : (m == 1) ? bk : bv;
        const float bias = Bp[lcol];

        if (m == 0) {
#pragma unroll
            for (int r = 0; r < 4; ++r)
                Qg[((size_t)b * NS + n0 + quad * 4 + r) * ND + lcol] =
                    (_Float16)((acc[r] + bias) * LOG2E);
        } else if (m == 1) {
#pragma unroll
            for (int r = 0; r < 4; ++r)
                Kg[((size_t)b * NS + n0 + quad * 4 + r) * ND + lcol] =
                    (_Float16)(acc[r] + bias);
        } else {
#pragma unroll
            for (int r = 0; r < 4; ++r)
                vt[wv][lcol * 20 + quad * 4 + r] = (_Float16)(acc[r] + bias);
        }
    }
    __syncthreads();
    {
        const int d = l;
        const _Float16* src = &vt[wv][d * 20];
        uint2 p0 = *(const uint2*)(src);
        uint2 p1 = *(const uint2*)(src + 4);
        uint2 p2 = *(const uint2*)(src + 8);
        uint2 p3 = *(const uint2*)(src + 12);
        uint4 q0 = {p0.x, p0.y, p1.x, p1.y};
        uint4 q1 = {p2.x, p2.y, p3.x, p3.y};
        _Float16* dst = Vt + ((size_t)b * ND + d) * NS + n0;
        *(uint4*)(dst)     = q0;
        *(uint4*)(dst + 8) = q1;
    }
}

// ---------------- fused masked attention: r3 structure + swizzle + 2 blk/CU --
// Block = 32 q-rows x 512 thr (8 waves = rh(2 row-halves of 16) x kq(4 key-
// quarters)). Grid 512 => 2 blocks/CU (LDS 37.9KB x2 = 75.8KB): one block's
// compute hides the other's barrier drains.
// LDS tiles keep 144B rows but every 16B chunk is XOR-swizzled by (row&7)
// (write AND read side; global sources stay linear). Hand-checked: staging
// ds_write_b128, K ds_read_b128, V 8B reads all land balanced (conflict-free).
// Pass 1: swapped QK mfma(kf,qf) -> lane reg r = score[key kq*16+quad*4+r][row
//   rh*16+tx]; L += exp2. Quad-reduce (shfl 16/32), kq-merge via lsh[4][32].
// Pass 2: recompute scores, w = e>L/N ? e/L : 0; lane's 4 w's ARE the A-frag
//   of v_mfma_f32_16x16x16_f16 -> PV direct from registers (zero exchange).
//   o[dg]: 16 rows x 64 dims x wave's key quarter; serial 4-step kq-merge
//   (two rh groups merge in parallel).
__global__ __launch_bounds__(512, 2) void attn(
    const _Float16* __restrict__ Qg,
    const _Float16* __restrict__ Kg,
    const _Float16* __restrict__ Vt,
    float* __restrict__ out)
{
    __shared__ __align__(16) _Float16 smem[2 * 64 * 72 + 2 * 64 * 72]; // ksm|vsm 36.9KB
    __shared__ float lsh[4 * 32];

    _Float16* ksm = smem;
    _Float16* vsm = smem + 2 * 64 * 72;

    const int tid  = threadIdx.x;
    const int wv   = tid >> 6;
    const int l    = tid & 63;
    const int quad = l >> 4;
    const int tx   = l & 15;
    const int rh   = wv >> 2;       // row-half (16 rows)
    const int kq   = wv & 3;        // key-quarter

    const int b  = blockIdx.x & 7;
    const int q0 = (blockIdx.x >> 3) * 32;

    const _Float16* Qb = Qg + ((size_t)b * NS + q0 + rh * 16) * ND;
    const _Float16* Kb = Kg + (size_t)b * NS * ND;
    const _Float16* Vb = Vt + (size_t)b * ND * NS;

    // Q B-frags: rows rh*16 + tx, k-chunks 0/1
    half8 qf[2];
#pragma unroll
    for (int kc = 0; kc < 2; ++kc)
        qf[kc] = *(const half8*)(Qb + (size_t)tx * ND + kc * 32 + quad * 8);

    // staging roles: thread -> 16B of each 8KB tile; LDS chunk XOR-swizzled
    const int skey = tid >> 3;
    const int sc   = tid & 7;
    const _Float16* Ksrc = Kb + (size_t)skey * ND + sc * 8;   // + t*64*ND
    const _Float16* Vsrc = Vb + (size_t)skey * NS + sc * 8;   // + t*64 (skey=dim)
    const int sdst = skey * 72 + ((sc ^ (skey & 7)) * 8);

    const floatx4 zf = {0.f, 0.f, 0.f, 0.f};
    const int t7    = tx & 7;
    const int krow  = (kq * 16 + tx) * 72;                 // K A-frag row base
    const int koff0 = (quad ^ t7) * 8;                     // chunk quad
    const int koff1 = ((quad ^ 4) ^ t7) * 8;               // chunk quad+4

    // ================= pass 1: L =================
    float lacc = 0.f;
    {
        uint4 gk = *(const uint4*)Ksrc;
        *(uint4*)(ksm + sdst) = gk;
        for (int t = 0; t < 32; ++t) {
            const int buf = (t & 1) * 4608;
            __syncthreads();
            if (t < 31) gk = *(const uint4*)(Ksrc + (size_t)(t + 1) * 64 * ND);
            half8 kf0 = *(const half8*)(ksm + buf + krow + koff0);
            half8 kf1 = *(const half8*)(ksm + buf + krow + koff1);
            floatx4 c = __builtin_amdgcn_mfma_f32_16x16x32_f16(kf0, qf[0], zf, 0, 0, 0);
            c = __builtin_amdgcn_mfma_f32_16x16x32_f16(kf1, qf[1], c, 0, 0, 0);
            lacc += __builtin_amdgcn_exp2f(c[0]) + __builtin_amdgcn_exp2f(c[1])
                  + __builtin_amdgcn_exp2f(c[2]) + __builtin_amdgcn_exp2f(c[3]);
            if (t < 31) *(uint4*)(ksm + (buf ^ 4608) + sdst) = gk;
        }
    }
    // reduce over quads (lanes tx, tx^16, tx^32, tx^48 share a q-row)
#pragma unroll
    for (int off = 16; off < 64; off <<= 1)
        lacc += __shfl_xor(lacc, off);
    if (quad == 0)
        lsh[kq * 32 + rh * 16 + tx] = lacc;

    // transition: prefetch tile 0 (K + V) over the merge barrier
    uint4 gk = *(const uint4*)Ksrc;
    uint4 gv = *(const uint4*)Vsrc;
    __syncthreads();                                // lsh ready; pass-1 LDS reads done

    float thr, inv;
    {
        const int row = rh * 16 + tx;
        float L = lsh[row] + lsh[32 + row] + lsh[64 + row] + lsh[96 + row];
        inv = 1.f / L;
        thr = L * (1.f / (float)NS);
    }

    *(uint4*)(ksm + sdst) = gk;
    *(uint4*)(vsm + sdst) = gv;     // vsmT[dim][72] — same swizzled layout

    // V B-frag offsets: row dg*16+tx, halfs kq*16+quad*4 -> swizzled chunk
    const int vchunk = ((kq * 2 + (quad >> 1)) ^ t7) * 8 + (quad & 1) * 4;

    floatx4 o[4] = {zf, zf, zf, zf};

    // ================= pass 2: recompute + mask + PV =================
    for (int t = 0; t < 32; ++t) {
        const int buf = (t & 1) * 4608;
        __syncthreads();                            // tiles staged & visible
        if (t < 31) {
            gk = *(const uint4*)(Ksrc + (size_t)(t + 1) * 64 * ND);
            gv = *(const uint4*)(Vsrc + (size_t)(t + 1) * 64);
        }
        half8 kf0 = *(const half8*)(ksm + buf + krow + koff0);
        half8 kf1 = *(const half8*)(ksm + buf + krow + koff1);
        half4 vf[4];
#pragma unroll
        for (int dg = 0; dg < 4; ++dg)
            vf[dg] = *(const half4*)(vsm + buf + (dg * 16 + tx) * 72 + vchunk);

        floatx4 c = __builtin_amdgcn_mfma_f32_16x16x32_f16(kf0, qf[0], zf, 0, 0, 0);
        c = __builtin_amdgcn_mfma_f32_16x16x32_f16(kf1, qf[1], c, 0, 0, 0);
        float e0 = __builtin_amdgcn_exp2f(c[0]);
        float e1 = __builtin_amdgcn_exp2f(c[1]);
        float e2 = __builtin_amdgcn_exp2f(c[2]);
        float e3 = __builtin_amdgcn_exp2f(c[3]);
        float w0 = (e0 > thr) ? e0 * inv : 0.f;
        float w1 = (e1 > thr) ? e1 * inv : 0.f;
        float w2 = (e2 > thr) ? e2 * inv : 0.f;
        float w3 = (e3 > thr) ? e3 * inv : 0.f;
        half4 af = {(_Float16)w0, (_Float16)w1, (_Float16)w2, (_Float16)w3};
#pragma unroll
        for (int dg = 0; dg < 4; ++dg)
            o[dg] = __builtin_amdgcn_mfma_f32_16x16x16f16(af, vf[dg], o[dg], 0, 0, 0);

        if (t < 31) {
            *(uint4*)(ksm + (buf ^ 4608) + sdst) = gk;
            *(uint4*)(vsm + (buf ^ 4608) + sdst) = gv;
        }
    }

    // ================= merge key-quarter partials, store =================
    __syncthreads();                                // all tile reads done
    float* osm = (float*)smem;                      // [32][68] overlay
    const int orow = rh * 16 + quad * 4;
    if (kq == 0) {
#pragma unroll
        for (int dg = 0; dg < 4; ++dg)
#pragma unroll
            for (int r = 0; r < 4; ++r)
                osm[(orow + r) * 68 + dg * 16 + tx] = o[dg][r];
    }
    __syncthreads();
    if (kq == 1) {
#pragma unroll
        for (int dg = 0; dg < 4; ++dg)
#pragma unroll
            for (int r = 0; r < 4; ++r)
                osm[(orow + r) * 68 + dg * 16 + tx] += o[dg][r];
    }
    __syncthreads();
    if (kq == 2) {
#pragma unroll
        for (int dg = 0; dg < 4; ++dg)
#pragma unroll
            for (int r = 0; r < 4; ++r)
                osm[(orow + r) * 68 + dg * 16 + tx] += o[dg][r];
    }
    __syncthreads();
    if (kq == 3) {
#pragma unroll
        for (int dg = 0; dg < 4; ++dg)
#pragma unroll
            for (int r = 0; r < 4; ++r)
                out[((size_t)b * NS + q0 + orow + r) * ND + dg * 16 + tx] =
                    osm[(orow + r) * 68 + dg * 16 + tx] + o[dg][r];
    }
}

extern "C" void kernel_launch(void* const* d_in, const int* in_sizes, int n_in,
                              void* d_out, int out_size, void* d_ws, size_t ws_size,
                              hipStream_t stream) {
    const float* x  = (const float*)d_in[0];
    const float* Wq = (const float*)d_in[1];
    const float* bq = (const float*)d_in[2];
    const float* Wk = (const float*)d_in[3];
    const float* bk = (const float*)d_in[4];
    const float* Wv = (const float*)d_in[5];
    const float* bv = (const float*)d_in[6];

    // ws: Qg(2MB) Kg(2MB) Vt(2MB) Wt(24KB)
    _Float16* Qg = (_Float16*)d_ws;
    _Float16* Kg = Qg + (size_t)NB * NS * ND;
    _Float16* Vt = Kg + (size_t)NB * NS * ND;
    _Float16* Wt = Vt + (size_t)NB * NS * ND;

    wprep<<<3, 256, 0, stream>>>(Wq, Wk, Wv, Wt);
    qkv_proj<<<NB * (NS / 64), 256, 0, stream>>>(x, Wt, bq, bk, bv, Qg, Kg, Vt);
    attn<<<NB * (NS / 32), 512, 0, stream>>>(Qg, Kg, Vt, (float*)d_out);
}